// Round 13
// baseline (321.751 us; speedup 1.0000x reference)
//
#include <hip/hip_runtime.h>
#include <math.h>

typedef __bf16 bf16_t;
typedef bf16_t bf16x8 __attribute__((ext_vector_type(8)));
typedef bf16_t bf16x4 __attribute__((ext_vector_type(4)));
typedef float  f32x4  __attribute__((ext_vector_type(4)));
typedef float  floatv4 __attribute__((ext_vector_type(4)));

#define AS1 __attribute__((address_space(1)))
#define AS3 __attribute__((address_space(3)))

static __device__ __forceinline__ void gld_lds16(const void* g, void* l) {
  __builtin_amdgcn_global_load_lds((const AS1 unsigned int*)g,
                                   (AS3 unsigned int*)l, 16, 0, 0);
}
static __device__ __forceinline__ void block_sync() {
  asm volatile("" ::: "memory");
  __builtin_amdgcn_s_barrier();
  asm volatile("" ::: "memory");
}

// ---------------- cast f32 -> bf16, 4 elems/thread ----------------
__global__ __launch_bounds__(256) void k_cast(const float* __restrict__ in,
                                              bf16_t* __restrict__ out, int n4) {
  int i = blockIdx.x * 256 + threadIdx.x;
  if (i >= n4) return;
  floatv4 v = ((const floatv4*)in)[i];
  bf16x4 o;
  o.x = (bf16_t)v.x; o.y = (bf16_t)v.y; o.z = (bf16_t)v.z; o.w = (bf16_t)v.w;
  ((bf16x4*)out)[i] = o;
}

// ---------------- transpose + cast: in f32 [R][Cc] -> out bf16 [Cc][R] ----------------
__global__ __launch_bounds__(256) void k_transpose_cast(const float* __restrict__ in,
                                                        bf16_t* __restrict__ out,
                                                        int R, int Cc) {
  __shared__ float tile[32][33];
  int c0 = blockIdx.x * 32, r0 = blockIdx.y * 32;
  int tx = threadIdx.x, ty = threadIdx.y;  // 32 x 8
#pragma unroll
  for (int i = 0; i < 32; i += 8)
    tile[ty + i][tx] = in[(size_t)(r0 + ty + i) * Cc + c0 + tx];
  __syncthreads();
#pragma unroll
  for (int i = 0; i < 32; i += 8)
    out[(size_t)(c0 + ty + i) * R + r0 + tx] = (bf16_t)tile[tx][ty + i];
}

// ============ GEMM v9: barrier-free wave-private pipeline ============
// Block 128x128, 4 waves (2M x 2N), per-wave 64x64 (acc[4][4]).
// Each wave owns a PRIVATE 2 x 8KB LDS double buffer (A 4KB + B 4KB, fragment-order,
// lane-linear). Per K-step: issue 8 gld_lds (next tile) -> vmcnt(8) waits exactly for
// the PREVIOUS batch -> 8 ds_read_b128 -> lgkmcnt(0) -> 16 MFMA. ZERO s_barrier in loop:
// waves fully self-paced (vmcnt is per-wave), barrier drain eliminated.
__global__ __launch_bounds__(256, 2) void k_gemm_qkv(
    const bf16_t* __restrict__ A, const bf16_t* __restrict__ Bt,
    const float* __restrict__ bias,
    bf16_t* __restrict__ qo, bf16_t* __restrict__ ko, bf16_t* __restrict__ vto) {
  const int K = 1024;
  __shared__ __align__(16) char smem[65536];  // 4 waves x 2 bufs x 8KB; epilogue reuses 33.8KB
  const int m0 = blockIdx.x * 128, n0 = blockIdx.y * 128;
  const int t = threadIdx.x, lane = t & 63, wv = t >> 6;
  const int ln15 = lane & 15, lhi = lane >> 4;
  const int wr = wv >> 1, wc = wv & 1;

  f32x4 acc[4][4];
#pragma unroll
  for (int m = 0; m < 4; ++m)
#pragma unroll
    for (int n = 0; n < 4; ++n) acc[m][n] = (f32x4){0.f, 0.f, 0.f, 0.f};

  char* myBase = smem + wv * 16384;  // wave-private partition
  const bf16_t* aB = A + (size_t)(m0 + wr * 64 + ln15) * K + lhi * 8;
  const bf16_t* bB = Bt + (size_t)(n0 + wc * 64 + ln15) * K + lhi * 8;
  const int lo = lane * 16;

  auto stage = [&](int k0, int bsel) {
    char* buf = myBase + bsel * 8192;
#pragma unroll
    for (int c = 0; c < 4; ++c)
      gld_lds16(aB + (size_t)c * 16 * K + k0, buf + c * 1024 + lo);
#pragma unroll
    for (int c = 0; c < 4; ++c)
      gld_lds16(bB + (size_t)c * 16 * K + k0, buf + 4096 + c * 1024 + lo);
  };

  stage(0, 0);
#pragma unroll 1
  for (int it = 0; it < 32; ++it) {
    if (it + 1 < 32) {
      stage((it + 1) * 32, (it + 1) & 1);
      asm volatile("s_waitcnt vmcnt(8)" ::: "memory");  // previous batch landed; 8 in flight
    } else {
      asm volatile("s_waitcnt vmcnt(0)" ::: "memory");
    }
    const char* bc = myBase + (it & 1) * 8192;
    bf16x8 af[4], bfr[4];
#pragma unroll
    for (int m = 0; m < 4; ++m)
      af[m] = *(const bf16x8*)(bc + m * 1024 + lo);
#pragma unroll
    for (int n = 0; n < 4; ++n)
      bfr[n] = *(const bf16x8*)(bc + 4096 + n * 1024 + lo);
    asm volatile("s_waitcnt lgkmcnt(0)" ::: "memory");
    __builtin_amdgcn_sched_barrier(0);
    __builtin_amdgcn_s_setprio(1);
#pragma unroll
    for (int m = 0; m < 4; ++m)
#pragma unroll
      for (int n = 0; n < 4; ++n)
        acc[m][n] = __builtin_amdgcn_mfma_f32_16x16x32_bf16(af[m], bfr[n], acc[m][n], 0, 0, 0);
    __builtin_amdgcn_s_setprio(0);
  }

  // epilogue: through LDS for coalesced 16B scatter (which uniform: n0 multiple of 128)
  const int which = n0 >> 10;  // 0=q 1=k 2=v
  const float bscale = (which == 0) ? 0.18033688011112042f : 1.0f;  // 0.125*log2(e)
  bf16_t* L = (bf16_t*)smem;
  block_sync();
#pragma unroll
  for (int n = 0; n < 4; ++n) {
    const int col = wc * 64 + n * 16 + ln15;
    const float bv = bias[n0 + col];
#pragma unroll
    for (int m = 0; m < 4; ++m)
#pragma unroll
      for (int j = 0; j < 4; ++j) {
        const int row = wr * 64 + m * 16 + lhi * 4 + j;
        const bf16_t ob = (bf16_t)((acc[m][n][j] + bv) * bscale);
        if (which == 2) L[col * 132 + row] = ob;   // v: [128 cols][132]
        else            L[row * 132 + col] = ob;   // q/k: [128 rows][132]
      }
  }
  block_sync();
  const int bq = m0 >> 11, ttb = m0 & 2047;
  if (which == 2) {
#pragma unroll
    for (int c = 0; c < 8; ++c) {
      const int idx = c * 256 + t;
      const int vcol = idx >> 4, r8 = (idx & 15) * 8;
      bf16x8 v8 = *(const bf16x8*)&L[vcol * 132 + r8];
      const int cc = (n0 + vcol) & 1023;
      const int hh = cc >> 6, d = cc & 63;
      *(bf16x8*)&vto[((size_t)(bq * 16 + hh) * 64 + d) * 2048 + ttb + r8] = v8;
    }
  } else {
    bf16_t* dst = (which == 0) ? qo : ko;
#pragma unroll
    for (int c = 0; c < 8; ++c) {
      const int idx = c * 256 + t;
      const int row = idx >> 4, c8 = (idx & 15) * 8;
      bf16x8 v8 = *(const bf16x8*)&L[row * 132 + c8];
      const int cc = (n0 & 1023) + c8;
      const int hh = cc >> 6, d = cc & 63;
      *(bf16x8*)&dst[((size_t)(bq * 16 + hh) * 2048 + ttb + row) * 64 + d] = v8;
    }
  }
}

// ---------------- flash attention v4.1: 32 q-rows/wave + setprio ----------------
__global__ __launch_bounds__(256) void k_attn4(
    const bf16_t* __restrict__ q, const bf16_t* __restrict__ k,
    const bf16_t* __restrict__ vt, const int* __restrict__ dirp,
    bf16_t* __restrict__ a2) {
  const int T = 2048;
  __shared__ __align__(16) bf16_t smem[16384];  // 32 KB: 2 bufs x 16KB
  const int bh = blockIdx.x, b = bh >> 4, h = bh & 15;
  const int jb = blockIdx.y;  // 0..7
  const int t = threadIdx.x, lane = t & 63, wv = t >> 6;
  const int ln15 = lane & 15, lhi = lane >> 4;
  const bool anti = (*dirp == 1);

  const bf16_t* kbase = k + (size_t)bh * T * 64;
  const bf16_t* vbase = vt + (size_t)bh * 64 * T;

  auto stage = [&](int kc0, int buf) {
    char* Kd = (char*)smem + buf * 16384;
    char* Vd = Kd + 8192;
#pragma unroll
    for (int s = 0; s < 2; ++s) {
      const int qk = s * 4 + wv;
      const int krow = kc0 + (qk >> 2) * 32 + ((qk >> 1) & 1) * 4 +
                       ((lane & 15) >> 2) * 8 + (lane & 3);
      const int kcolb = (lane >> 4) * 16 + (qk & 1) * 64;
      gld_lds16((const char*)kbase + (size_t)krow * 128 + kcolb,
                Kd + s * 4096 + t * 16);
      const int vd = (qk & 3) * 16 + (lane & 15);
      gld_lds16((const char*)vbase + (size_t)vd * 4096 + (size_t)kc0 * 2 +
                    (qk >> 2) * 64 + (lane >> 4) * 16,
                Vd + s * 4096 + t * 16);
    }
  };

#pragma unroll 1
  for (int sel = 0; sel < 2; ++sel) {
    const int qt = sel ? (15 - jb) : jb;     // q-tile of 128 rows
    const int q0w = qt * 128 + wv * 32;      // this wave's 32 rows

    bf16x8 qf[2][2];
#pragma unroll
    for (int g = 0; g < 2; ++g) {
      const bf16_t* qp = q + ((size_t)bh * T + q0w + g * 16 + ln15) * 64 + lhi * 8;
      qf[g][0] = *(const bf16x8*)qp;
      qf[g][1] = *(const bf16x8*)(qp + 32);
    }

    f32x4 acc[2][4];
#pragma unroll
    for (int g = 0; g < 2; ++g)
#pragma unroll
      for (int dg = 0; dg < 4; ++dg) acc[g][dg] = (f32x4){0.f, 0.f, 0.f, 0.f};
    float mrun[2] = {-3.0e38f, -3.0e38f}, lrun[2] = {0.f, 0.f};

    const int kt0 = anti ? 2 * qt : 0;
    const int nb  = anti ? (32 - 2 * qt) : (2 * qt + 2);

    stage(kt0 * 64, 0);
#pragma unroll 1
    for (int i = 0; i < nb; ++i) {
      const int kt = kt0 + i;
      const int buf = i & 1;
      if (i + 1 < nb) {
        stage((kt + 1) * 64, buf ^ 1);
        asm volatile("s_waitcnt vmcnt(4)" ::: "memory");
      } else {
        asm volatile("s_waitcnt vmcnt(0)" ::: "memory");
      }
      block_sync();
      const bf16_t* Kb = smem + buf * 8192;  // bf16 units
      const bf16_t* Vb = Kb + 4096;

      const bool active = anti ? (kt * 64 + 63 >= q0w) : (kt * 64 <= q0w + 31);
      if (active) {
        float sc[2][16];
#pragma unroll
        for (int kh = 0; kh < 2; ++kh) {
          bf16x8 kf0 = *(const bf16x8*)(Kb + (kh * 4 + 0) * 512 + lane * 8);
          bf16x8 kf1 = *(const bf16x8*)(Kb + (kh * 4 + 1) * 512 + lane * 8);
          bf16x8 kf2 = *(const bf16x8*)(Kb + (kh * 4 + 2) * 512 + lane * 8);
          bf16x8 kf3 = *(const bf16x8*)(Kb + (kh * 4 + 3) * 512 + lane * 8);
          __builtin_amdgcn_s_setprio(1);
#pragma unroll
          for (int g = 0; g < 2; ++g) {
            const f32x4 zz = (f32x4){0.f, 0.f, 0.f, 0.f};
            f32x4 slo = __builtin_amdgcn_mfma_f32_16x16x32_bf16(kf0, qf[g][0], zz, 0, 0, 0);
            slo = __builtin_amdgcn_mfma_f32_16x16x32_bf16(kf1, qf[g][1], slo, 0, 0, 0);
            f32x4 shi = __builtin_amdgcn_mfma_f32_16x16x32_bf16(kf2, qf[g][0], zz, 0, 0, 0);
            shi = __builtin_amdgcn_mfma_f32_16x16x32_bf16(kf3, qf[g][1], shi, 0, 0, 0);
#pragma unroll
            for (int j = 0; j < 4; ++j) {
              sc[g][kh * 8 + j] = slo[j];
              sc[g][kh * 8 + 4 + j] = shi[j];
            }
          }
          __builtin_amdgcn_s_setprio(0);
        }
        bf16x8 vfr[8];
#pragma unroll
        for (int dg = 0; dg < 8; ++dg)
          vfr[dg] = *(const bf16x8*)(Vb + dg * 512 + lane * 8);
#pragma unroll
        for (int g = 0; g < 2; ++g) {
          const int grow = q0w + g * 16 + ln15;
          const bool needm = anti ? (kt * 64 < q0w + g * 16 + 15)
                                  : (kt * 64 + 63 > q0w + g * 16);
          if (needm) {
#pragma unroll
            for (int e = 0; e < 16; ++e) {
              const int col = kt * 64 + (e >> 3) * 32 + lhi * 8 + (e & 7);
              const bool ok = anti ? (col >= grow) : (col <= grow);
              sc[g][e] = ok ? sc[g][e] : -3.0e38f;
            }
          }
          float lmax = sc[g][0];
#pragma unroll
          for (int e = 1; e < 16; ++e) lmax = fmaxf(lmax, sc[g][e]);
          if (!__all(lmax <= mrun[g] + 8.f)) {
            float vm = lmax;
            vm = fmaxf(vm, __shfl_xor(vm, 16));
            vm = fmaxf(vm, __shfl_xor(vm, 32));
            const float mn = fmaxf(mrun[g], vm);
            const float al = __builtin_amdgcn_exp2f(mrun[g] - mn);
            lrun[g] *= al;
#pragma unroll
            for (int dg = 0; dg < 4; ++dg) acc[g][dg] *= al;
            mrun[g] = mn;
          }
          bf16x8 pb0, pb1;
          float rs = 0.f;
#pragma unroll
          for (int e = 0; e < 8; ++e) {
            float p = __builtin_amdgcn_exp2f(sc[g][e] - mrun[g]);
            rs += p; pb0[e] = (bf16_t)p;
          }
#pragma unroll
          for (int e = 0; e < 8; ++e) {
            float p = __builtin_amdgcn_exp2f(sc[g][8 + e] - mrun[g]);
            rs += p; pb1[e] = (bf16_t)p;
          }
          lrun[g] += rs;
          __builtin_amdgcn_s_setprio(1);
#pragma unroll
          for (int dg = 0; dg < 4; ++dg)
            acc[g][dg] = __builtin_amdgcn_mfma_f32_16x16x32_bf16(vfr[dg], pb0, acc[g][dg], 0, 0, 0);
#pragma unroll
          for (int dg = 0; dg < 4; ++dg)
            acc[g][dg] = __builtin_amdgcn_mfma_f32_16x16x32_bf16(vfr[4 + dg], pb1, acc[g][dg], 0, 0, 0);
          __builtin_amdgcn_s_setprio(0);
        }
      }
      block_sync();
    }

#pragma unroll
    for (int g = 0; g < 2; ++g) {
      float l = lrun[g];
      l += __shfl_xor(l, 16);
      l += __shfl_xor(l, 32);
      const float inv = __builtin_amdgcn_rcpf(l);
      bf16_t* op = a2 + ((size_t)b * T + q0w + g * 16 + ln15) * 1024 + h * 64 + lhi * 4;
#pragma unroll
      for (int dg = 0; dg < 4; ++dg) {
        bf16x4 o4;
#pragma unroll
        for (int jx = 0; jx < 4; ++jx) o4[jx] = (bf16_t)(acc[g][dg][jx] * inv);
        *(bf16x4*)(op + dg * 16) = o4;
      }
    }
  }
}

// ============ GEMM2 v9: barrier-free wave-private pipeline, fp32 out ============
__global__ __launch_bounds__(256, 2) void k_gemm_proj(
    const bf16_t* __restrict__ A, const bf16_t* __restrict__ Bt,
    const float* __restrict__ bias, float* __restrict__ out) {
  const int K = 1024;
  __shared__ __align__(16) char smem[65536];
  const int m0 = blockIdx.x * 128, n0 = blockIdx.y * 128;
  const int t = threadIdx.x, lane = t & 63, wv = t >> 6;
  const int ln15 = lane & 15, lhi = lane >> 4;
  const int wr = wv >> 1, wc = wv & 1;

  f32x4 acc[4][4];
#pragma unroll
  for (int m = 0; m < 4; ++m)
#pragma unroll
    for (int n = 0; n < 4; ++n) acc[m][n] = (f32x4){0.f, 0.f, 0.f, 0.f};

  char* myBase = smem + wv * 16384;
  const bf16_t* aB = A + (size_t)(m0 + wr * 64 + ln15) * K + lhi * 8;
  const bf16_t* bB = Bt + (size_t)(n0 + wc * 64 + ln15) * K + lhi * 8;
  const int lo = lane * 16;

  auto stage = [&](int k0, int bsel) {
    char* buf = myBase + bsel * 8192;
#pragma unroll
    for (int c = 0; c < 4; ++c)
      gld_lds16(aB + (size_t)c * 16 * K + k0, buf + c * 1024 + lo);
#pragma unroll
    for (int c = 0; c < 4; ++c)
      gld_lds16(bB + (size_t)c * 16 * K + k0, buf + 4096 + c * 1024 + lo);
  };

  stage(0, 0);
#pragma unroll 1
  for (int it = 0; it < 32; ++it) {
    if (it + 1 < 32) {
      stage((it + 1) * 32, (it + 1) & 1);
      asm volatile("s_waitcnt vmcnt(8)" ::: "memory");
    } else {
      asm volatile("s_waitcnt vmcnt(0)" ::: "memory");
    }
    const char* bc = myBase + (it & 1) * 8192;
    bf16x8 af[4], bfr[4];
#pragma unroll
    for (int m = 0; m < 4; ++m)
      af[m] = *(const bf16x8*)(bc + m * 1024 + lo);
#pragma unroll
    for (int n = 0; n < 4; ++n)
      bfr[n] = *(const bf16x8*)(bc + 4096 + n * 1024 + lo);
    asm volatile("s_waitcnt lgkmcnt(0)" ::: "memory");
    __builtin_amdgcn_sched_barrier(0);
    __builtin_amdgcn_s_setprio(1);
#pragma unroll
    for (int m = 0; m < 4; ++m)
#pragma unroll
      for (int n = 0; n < 4; ++n)
        acc[m][n] = __builtin_amdgcn_mfma_f32_16x16x32_bf16(af[m], bfr[n], acc[m][n], 0, 0, 0);
    __builtin_amdgcn_s_setprio(0);
  }

#pragma unroll
  for (int n = 0; n < 4; ++n) {
    const int col = n0 + wc * 64 + n * 16 + ln15;
    const float bv = bias[col];
#pragma unroll
    for (int m = 0; m < 4; ++m)
#pragma unroll
      for (int j = 0; j < 4; ++j) {
        const int row = m0 + wr * 64 + m * 16 + lhi * 4 + j;
        out[(size_t)row * 1024 + col] = acc[m][n][j] + bv;
      }
  }
}

extern "C" void kernel_launch(void* const* d_in, const int* in_sizes, int n_in,
                              void* d_out, int out_size, void* d_ws, size_t ws_size,
                              hipStream_t stream) {
  (void)in_sizes; (void)n_in; (void)out_size; (void)ws_size;
  const float* x      = (const float*)d_in[0];
  const int*   dirp   = (const int*)d_in[1];
  const float* qkv_w  = (const float*)d_in[2];
  const float* qkv_b  = (const float*)d_in[3];
  const float* proj_w = (const float*)d_in[4];
  const float* proj_b = (const float*)d_in[5];
  float* out = (float*)d_out;

  char* ws = (char*)d_ws;
  bf16_t* xb   = (bf16_t*)(ws);                       // 16,777,216 B (reused as a2)
  bf16_t* wq_t = (bf16_t*)(ws + 16777216);            //  6,291,456 B
  bf16_t* wp_t = (bf16_t*)(ws + 23068672);            //  2,097,152 B
  bf16_t* qb   = (bf16_t*)(ws + 25165824);            // 16,777,216 B
  bf16_t* kb   = (bf16_t*)(ws + 41943040);            // 16,777,216 B
  bf16_t* vtb  = (bf16_t*)(ws + 58720256);            // 16,777,216 B (end: 75,497,472)
  bf16_t* a2   = xb;

  k_cast<<<8192, 256, 0, stream>>>(x, xb, 2097152);
  k_transpose_cast<<<dim3(96, 32), dim3(32, 8), 0, stream>>>(qkv_w, wq_t, 1024, 3072);
  k_transpose_cast<<<dim3(32, 32), dim3(32, 8), 0, stream>>>(proj_w, wp_t, 1024, 1024);
  k_gemm_qkv<<<dim3(64, 24), 256, 0, stream>>>(xb, wq_t, qkv_b, qb, kb, vtb);
  k_attn4<<<dim3(64, 8), 256, 0, stream>>>(qb, kb, vtb, dirp, a2);
  k_gemm_proj<<<dim3(64, 8), 256, 0, stream>>>(a2, wp_t, proj_b, out);
}

// Round 14
// 213.823 us; speedup vs baseline: 1.5048x; 1.5048x over previous
//
#include <hip/hip_runtime.h>
#include <math.h>

typedef __bf16 bf16_t;
typedef bf16_t bf16x8 __attribute__((ext_vector_type(8)));
typedef bf16_t bf16x4 __attribute__((ext_vector_type(4)));
typedef float  f32x4  __attribute__((ext_vector_type(4)));
typedef float  f32x16 __attribute__((ext_vector_type(16)));
typedef float  floatv4 __attribute__((ext_vector_type(4)));

#define AS1 __attribute__((address_space(1)))
#define AS3 __attribute__((address_space(3)))

static __device__ __forceinline__ void gld_lds16(const void* g, void* l) {
  __builtin_amdgcn_global_load_lds((const AS1 unsigned int*)g,
                                   (AS3 unsigned int*)l, 16, 0, 0);
}
static __device__ __forceinline__ void block_sync() {
  asm volatile("" ::: "memory");
  __builtin_amdgcn_s_barrier();
  asm volatile("" ::: "memory");
}

// ---------------- cast f32 -> bf16, 4 elems/thread ----------------
__global__ __launch_bounds__(256) void k_cast(const float* __restrict__ in,
                                              bf16_t* __restrict__ out, int n4) {
  int i = blockIdx.x * 256 + threadIdx.x;
  if (i >= n4) return;
  floatv4 v = ((const floatv4*)in)[i];
  bf16x4 o;
  o.x = (bf16_t)v.x; o.y = (bf16_t)v.y; o.z = (bf16_t)v.z; o.w = (bf16_t)v.w;
  ((bf16x4*)out)[i] = o;
}

// ---------------- transpose + cast: in f32 [R][Cc] -> out bf16 [Cc][R] ----------------
__global__ __launch_bounds__(256) void k_transpose_cast(const float* __restrict__ in,
                                                        bf16_t* __restrict__ out,
                                                        int R, int Cc) {
  __shared__ float tile[32][33];
  int c0 = blockIdx.x * 32, r0 = blockIdx.y * 32;
  int tx = threadIdx.x, ty = threadIdx.y;  // 32 x 8
#pragma unroll
  for (int i = 0; i < 32; i += 8)
    tile[ty + i][tx] = in[(size_t)(r0 + ty + i) * Cc + c0 + tx];
  __syncthreads();
#pragma unroll
  for (int i = 0; i < 32; i += 8)
    out[(size_t)(c0 + ty + i) * R + r0 + tx] = (bf16_t)tile[tx][ty + i];
}

// ============ GEMM1 v10: R8-v6 structure + 32x32x16 MFMA inner tile ============
// 256x384, BK=32, 8 waves (2M x 4N), per-wave 128x96 = 4m x 3n tiles of 32x32.
// LDS slices: 32 rows x 16 k = 1KB, lane-linear (row=lane&31, k-half=lane>>5).
// A: 16 slices (s=kk*8+mi); B at +16384: 24 slices (s=kk*12+ni). 3 bufs, depth-2,
// vmcnt(5) at step end only. 2 phases/step: P1 m-tiles 0..1 (24->12 MFMA), P2 m-tiles 2..3.
__global__ __launch_bounds__(512, 2) void k_gemm_qkv(
    const bf16_t* __restrict__ A, const bf16_t* __restrict__ Bt,
    const float* __restrict__ bias,
    bf16_t* __restrict__ qo, bf16_t* __restrict__ ko, bf16_t* __restrict__ vto) {
  const int K = 1024;
  __shared__ __align__(16) char smem[122880];  // 3 x 40KB; epilogue reuses 68KB
  const int m0 = blockIdx.x * 256, n0 = blockIdx.y * 384;
  const int t = threadIdx.x, lane = t & 63, wv = t >> 6;
  const int ln31 = lane & 31, khalf = lane >> 5;
  const int wr = wv >> 2, wc = wv & 3;  // 2M x 4N; per-wave 128 x 96

  f32x16 acc[4][3];
#pragma unroll
  for (int m = 0; m < 4; ++m)
#pragma unroll
    for (int n = 0; n < 3; ++n)
#pragma unroll
      for (int e = 0; e < 16; ++e) acc[m][n][e] = 0.f;
  bf16x8 af[4], bfr[6];

  // stage sources (fragment-order slices: row = base + ln31, k = k0 + kk*16 + khalf*8)
  const bf16_t* aS = A + (size_t)(m0 + wv * 32 + ln31) * K + khalf * 8;
  const bf16_t* bS0 = Bt + (size_t)(n0 + ln31) * K + khalf * 8;

  auto stageA = [&](int k0, char* buf) {
    gld_lds16(aS + k0, buf + (size_t)wv * 1024 + lane * 16);           // kk0, mi=wv
    gld_lds16(aS + k0 + 16, buf + (size_t)(8 + wv) * 1024 + lane * 16); // kk1, mi=wv
  };
  auto stageB = [&](int k0, char* buf) {
#pragma unroll
    for (int j = 0; j < 3; ++j) {
      const int sl = j * 8 + wv;            // 0..23
      const int kk = (sl >= 12) ? 1 : 0;
      const int ni = sl - kk * 12;
      gld_lds16(bS0 + (size_t)ni * 32 * K + k0 + kk * 16,
                buf + 16384 + (size_t)sl * 1024 + lane * 16);
    }
  };

  char* b0 = smem;
  char* b1 = smem + 40960;
  char* b2 = smem + 81920;
  stageA(0, b0); stageB(0, b0);
  stageA(32, b1); stageB(32, b1);
  asm volatile("s_waitcnt vmcnt(5)" ::: "memory");
  block_sync();

#pragma unroll 1
  for (int it = 0; it < 32; ++it) {
    const bool st = (it + 2 < 32);
    const int k0n = (it + 2) * 32;
    // P1: m-tiles 0..1, both kk, all 3 n
#pragma unroll
    for (int kk = 0; kk < 2; ++kk)
#pragma unroll
      for (int i = 0; i < 2; ++i)
        af[kk * 2 + i] = *(const bf16x8*)(b0 + (size_t)(kk * 8 + wr * 4 + i) * 1024 + lane * 16);
#pragma unroll
    for (int kk = 0; kk < 2; ++kk)
#pragma unroll
      for (int n = 0; n < 3; ++n)
        bfr[kk * 3 + n] = *(const bf16x8*)(b0 + 16384 + (size_t)(kk * 12 + wc * 3 + n) * 1024 + lane * 16);
    if (st) stageA(k0n, b2);
    block_sync();
    asm volatile("s_waitcnt lgkmcnt(0)" ::: "memory");
    __builtin_amdgcn_sched_barrier(0);
    __builtin_amdgcn_s_setprio(1);
#pragma unroll
    for (int kk = 0; kk < 2; ++kk)
#pragma unroll
      for (int i = 0; i < 2; ++i)
#pragma unroll
        for (int n = 0; n < 3; ++n)
          acc[i][n] = __builtin_amdgcn_mfma_f32_32x32x16_bf16(af[kk * 2 + i], bfr[kk * 3 + n], acc[i][n], 0, 0, 0);
    __builtin_amdgcn_s_setprio(0);
    block_sync();
    // P2: m-tiles 2..3 (B frags reused from registers)
#pragma unroll
    for (int kk = 0; kk < 2; ++kk)
#pragma unroll
      for (int i = 0; i < 2; ++i)
        af[kk * 2 + i] = *(const bf16x8*)(b0 + (size_t)(kk * 8 + wr * 4 + 2 + i) * 1024 + lane * 16);
    if (st) stageB(k0n, b2);
    block_sync();
    asm volatile("s_waitcnt lgkmcnt(0)" ::: "memory");
    __builtin_amdgcn_sched_barrier(0);
    __builtin_amdgcn_s_setprio(1);
#pragma unroll
    for (int kk = 0; kk < 2; ++kk)
#pragma unroll
      for (int i = 0; i < 2; ++i)
#pragma unroll
        for (int n = 0; n < 3; ++n)
          acc[2 + i][n] = __builtin_amdgcn_mfma_f32_32x32x16_bf16(af[kk * 2 + i], bfr[kk * 3 + n], acc[2 + i][n], 0, 0, 0);
    __builtin_amdgcn_s_setprio(0);
    if (st) asm volatile("s_waitcnt vmcnt(5)" ::: "memory");
    else if (it + 1 < 32) asm volatile("s_waitcnt vmcnt(0)" ::: "memory");
    block_sync();
    char* tmp = b0; b0 = b1; b1 = b2; b2 = tmp;
  }

  // epilogue: 3 passes of 128 cols; C/D layout: col=lane&31, row=(r&3)+8*(r>>2)+4*(lane>>5)
  bf16_t* L = (bf16_t*)smem;
  const int bq = m0 >> 11, ttb = m0 & 2047;
#pragma unroll 1
  for (int p = 0; p < 3; ++p) {
    const int wcol0 = n0 + p * 128;
    const int which = wcol0 >> 10;  // uniform per pass
    const float bscale = (which == 0) ? 0.18033688011112042f : 1.0f;  // 0.125*log2(e)
#pragma unroll
    for (int n = 0; n < 3; ++n) {
      const int nt = wc * 3 + n;          // 0..11
      if ((nt >> 2) == p) {
        const int colL = (nt & 3) * 32 + ln31;
        const float bv = bias[n0 + nt * 32 + ln31];
#pragma unroll
        for (int m = 0; m < 4; ++m)
#pragma unroll
          for (int r = 0; r < 16; ++r) {
            const int row = wr * 128 + m * 32 + (r & 3) + 8 * (r >> 2) + 4 * khalf;
            const bf16_t ob = (bf16_t)((acc[m][n][r] + bv) * bscale);
            if (which == 2) L[colL * 264 + row] = ob;   // v: col-major [128][264]
            else            L[row * 132 + colL] = ob;   // q/k: row-major [256][132]
          }
      }
    }
    block_sync();
    if (which == 2) {
#pragma unroll
      for (int c = 0; c < 8; ++c) {
        const int idx = c * 512 + t;
        const int vcol = idx >> 5, r8 = (idx & 31) * 8;
        bf16x8 v8 = *(const bf16x8*)&L[vcol * 264 + r8];
        const int cc = (wcol0 & 1023) + vcol;
        const int hh = cc >> 6, d = cc & 63;
        *(bf16x8*)&vto[((size_t)(bq * 16 + hh) * 64 + d) * 2048 + ttb + r8] = v8;
      }
    } else {
      bf16_t* dst = (which == 0) ? qo : ko;
#pragma unroll
      for (int c = 0; c < 8; ++c) {
        const int idx = c * 512 + t;
        const int row = idx >> 4, c8 = (idx & 15) * 8;
        bf16x8 v8 = *(const bf16x8*)&L[row * 132 + c8];
        const int cc = (wcol0 & 1023) + c8;
        const int hh = cc >> 6, d = cc & 63;
        *(bf16x8*)&dst[((size_t)(bq * 16 + hh) * 2048 + ttb + row) * 64 + d] = v8;
      }
    }
    block_sync();
  }
}

// ---------------- flash attention v4.1: 32 q-rows/wave + setprio ----------------
__global__ __launch_bounds__(256) void k_attn4(
    const bf16_t* __restrict__ q, const bf16_t* __restrict__ k,
    const bf16_t* __restrict__ vt, const int* __restrict__ dirp,
    bf16_t* __restrict__ a2) {
  const int T = 2048;
  __shared__ __align__(16) bf16_t smem[16384];  // 32 KB: 2 bufs x 16KB
  const int bh = blockIdx.x, b = bh >> 4, h = bh & 15;
  const int jb = blockIdx.y;  // 0..7
  const int t = threadIdx.x, lane = t & 63, wv = t >> 6;
  const int ln15 = lane & 15, lhi = lane >> 4;
  const bool anti = (*dirp == 1);

  const bf16_t* kbase = k + (size_t)bh * T * 64;
  const bf16_t* vbase = vt + (size_t)bh * 64 * T;

  auto stage = [&](int kc0, int buf) {
    char* Kd = (char*)smem + buf * 16384;
    char* Vd = Kd + 8192;
#pragma unroll
    for (int s = 0; s < 2; ++s) {
      const int qk = s * 4 + wv;
      const int krow = kc0 + (qk >> 2) * 32 + ((qk >> 1) & 1) * 4 +
                       ((lane & 15) >> 2) * 8 + (lane & 3);
      const int kcolb = (lane >> 4) * 16 + (qk & 1) * 64;
      gld_lds16((const char*)kbase + (size_t)krow * 128 + kcolb,
                Kd + s * 4096 + t * 16);
      const int vd = (qk & 3) * 16 + (lane & 15);
      gld_lds16((const char*)vbase + (size_t)vd * 4096 + (size_t)kc0 * 2 +
                    (qk >> 2) * 64 + (lane >> 4) * 16,
                Vd + s * 4096 + t * 16);
    }
  };

#pragma unroll 1
  for (int sel = 0; sel < 2; ++sel) {
    const int qt = sel ? (15 - jb) : jb;     // q-tile of 128 rows
    const int q0w = qt * 128 + wv * 32;      // this wave's 32 rows

    bf16x8 qf[2][2];
#pragma unroll
    for (int g = 0; g < 2; ++g) {
      const bf16_t* qp = q + ((size_t)bh * T + q0w + g * 16 + ln15) * 64 + lhi * 8;
      qf[g][0] = *(const bf16x8*)qp;
      qf[g][1] = *(const bf16x8*)(qp + 32);
    }

    f32x4 acc[2][4];
#pragma unroll
    for (int g = 0; g < 2; ++g)
#pragma unroll
      for (int dg = 0; dg < 4; ++dg) acc[g][dg] = (f32x4){0.f, 0.f, 0.f, 0.f};
    float mrun[2] = {-3.0e38f, -3.0e38f}, lrun[2] = {0.f, 0.f};

    const int kt0 = anti ? 2 * qt : 0;
    const int nb  = anti ? (32 - 2 * qt) : (2 * qt + 2);

    stage(kt0 * 64, 0);
#pragma unroll 1
    for (int i = 0; i < nb; ++i) {
      const int kt = kt0 + i;
      const int buf = i & 1;
      if (i + 1 < nb) {
        stage((kt + 1) * 64, buf ^ 1);
        asm volatile("s_waitcnt vmcnt(4)" ::: "memory");
      } else {
        asm volatile("s_waitcnt vmcnt(0)" ::: "memory");
      }
      block_sync();
      const bf16_t* Kb = smem + buf * 8192;  // bf16 units
      const bf16_t* Vb = Kb + 4096;

      const bool active = anti ? (kt * 64 + 63 >= q0w) : (kt * 64 <= q0w + 31);
      if (active) {
        float sc[2][16];
#pragma unroll
        for (int kh = 0; kh < 2; ++kh) {
          bf16x8 kf0 = *(const bf16x8*)(Kb + (kh * 4 + 0) * 512 + lane * 8);
          bf16x8 kf1 = *(const bf16x8*)(Kb + (kh * 4 + 1) * 512 + lane * 8);
          bf16x8 kf2 = *(const bf16x8*)(Kb + (kh * 4 + 2) * 512 + lane * 8);
          bf16x8 kf3 = *(const bf16x8*)(Kb + (kh * 4 + 3) * 512 + lane * 8);
          __builtin_amdgcn_s_setprio(1);
#pragma unroll
          for (int g = 0; g < 2; ++g) {
            const f32x4 zz = (f32x4){0.f, 0.f, 0.f, 0.f};
            f32x4 slo = __builtin_amdgcn_mfma_f32_16x16x32_bf16(kf0, qf[g][0], zz, 0, 0, 0);
            slo = __builtin_amdgcn_mfma_f32_16x16x32_bf16(kf1, qf[g][1], slo, 0, 0, 0);
            f32x4 shi = __builtin_amdgcn_mfma_f32_16x16x32_bf16(kf2, qf[g][0], zz, 0, 0, 0);
            shi = __builtin_amdgcn_mfma_f32_16x16x32_bf16(kf3, qf[g][1], shi, 0, 0, 0);
#pragma unroll
            for (int j = 0; j < 4; ++j) {
              sc[g][kh * 8 + j] = slo[j];
              sc[g][kh * 8 + 4 + j] = shi[j];
            }
          }
          __builtin_amdgcn_s_setprio(0);
        }
        bf16x8 vfr[8];
#pragma unroll
        for (int dg = 0; dg < 8; ++dg)
          vfr[dg] = *(const bf16x8*)(Vb + dg * 512 + lane * 8);
#pragma unroll
        for (int g = 0; g < 2; ++g) {
          const int grow = q0w + g * 16 + ln15;
          const bool needm = anti ? (kt * 64 < q0w + g * 16 + 15)
                                  : (kt * 64 + 63 > q0w + g * 16);
          if (needm) {
#pragma unroll
            for (int e = 0; e < 16; ++e) {
              const int col = kt * 64 + (e >> 3) * 32 + lhi * 8 + (e & 7);
              const bool ok = anti ? (col >= grow) : (col <= grow);
              sc[g][e] = ok ? sc[g][e] : -3.0e38f;
            }
          }
          float lmax = sc[g][0];
#pragma unroll
          for (int e = 1; e < 16; ++e) lmax = fmaxf(lmax, sc[g][e]);
          if (!__all(lmax <= mrun[g] + 8.f)) {
            float vm = lmax;
            vm = fmaxf(vm, __shfl_xor(vm, 16));
            vm = fmaxf(vm, __shfl_xor(vm, 32));
            const float mn = fmaxf(mrun[g], vm);
            const float al = __builtin_amdgcn_exp2f(mrun[g] - mn);
            lrun[g] *= al;
#pragma unroll
            for (int dg = 0; dg < 4; ++dg) acc[g][dg] *= al;
            mrun[g] = mn;
          }
          bf16x8 pb0, pb1;
          float rs = 0.f;
#pragma unroll
          for (int e = 0; e < 8; ++e) {
            float p = __builtin_amdgcn_exp2f(sc[g][e] - mrun[g]);
            rs += p; pb0[e] = (bf16_t)p;
          }
#pragma unroll
          for (int e = 0; e < 8; ++e) {
            float p = __builtin_amdgcn_exp2f(sc[g][8 + e] - mrun[g]);
            rs += p; pb1[e] = (bf16_t)p;
          }
          lrun[g] += rs;
          __builtin_amdgcn_s_setprio(1);
#pragma unroll
          for (int dg = 0; dg < 4; ++dg)
            acc[g][dg] = __builtin_amdgcn_mfma_f32_16x16x32_bf16(vfr[dg], pb0, acc[g][dg], 0, 0, 0);
#pragma unroll
          for (int dg = 0; dg < 4; ++dg)
            acc[g][dg] = __builtin_amdgcn_mfma_f32_16x16x32_bf16(vfr[4 + dg], pb1, acc[g][dg], 0, 0, 0);
          __builtin_amdgcn_s_setprio(0);
        }
      }
      block_sync();
    }

#pragma unroll
    for (int g = 0; g < 2; ++g) {
      float l = lrun[g];
      l += __shfl_xor(l, 16);
      l += __shfl_xor(l, 32);
      const float inv = __builtin_amdgcn_rcpf(l);
      bf16_t* op = a2 + ((size_t)b * T + q0w + g * 16 + ln15) * 1024 + h * 64 + lhi * 4;
#pragma unroll
      for (int dg = 0; dg < 4; ++dg) {
        bf16x4 o4;
#pragma unroll
        for (int jx = 0; jx < 4; ++jx) o4[jx] = (bf16_t)(acc[g][dg][jx] * inv);
        *(bf16x4*)(op + dg * 16) = o4;
      }
    }
  }
}

// ============ GEMM2 v6: 256x128 tile, BK=32, 8 waves, grid 32x8=256 (zero tail) ============
__global__ __launch_bounds__(512, 2) void k_gemm_proj(
    const bf16_t* __restrict__ A, const bf16_t* __restrict__ Bt,
    const float* __restrict__ bias, float* __restrict__ out) {
  const int K = 1024;
  __shared__ __align__(16) char smem[73728];  // 3 x 24KB
  const int m0 = blockIdx.x * 256, n0 = blockIdx.y * 128;
  const int t = threadIdx.x, lane = t & 63, wv = t >> 6;
  const int ln15 = lane & 15, lhi = lane >> 4;
  const int wr = wv >> 2, wc = wv & 3;  // 2M x 4N; per-wave 128 x 32

  f32x4 acc[8][2];
#pragma unroll
  for (int m = 0; m < 8; ++m)
#pragma unroll
    for (int n = 0; n < 2; ++n) acc[m][n] = (f32x4){0.f, 0.f, 0.f, 0.f};
  bf16x8 af[4], bfr[2];

  const bf16_t* aS = A + (size_t)(m0 + wv * 16 + ln15) * K + lhi * 8;
  const bf16_t* bS = Bt + (size_t)(n0 + wv * 16 + ln15) * K + lhi * 8;
  const int dA = wv * 1024 + lane * 16;

  auto stageA = [&](int k0, char* buf) {
    gld_lds16(aS + k0, buf + dA);
    gld_lds16(aS + (size_t)128 * K + k0, buf + 8192 + dA);
  };
  auto stageB = [&](int k0, char* buf) {
    gld_lds16(bS + k0, buf + 16384 + dA);
  };

  char* b0 = smem;
  char* b1 = smem + 24576;
  char* b2 = smem + 49152;
  stageA(0, b0); stageB(0, b0);
  stageA(32, b1); stageB(32, b1);
  asm volatile("s_waitcnt vmcnt(3)" ::: "memory");
  block_sync();

#pragma unroll 1
  for (int it = 0; it < 32; ++it) {
    const bool st = (it + 2 < 32);
    const int k0n = (it + 2) * 32;
    // P1
#pragma unroll
    for (int m = 0; m < 4; ++m)
      af[m] = *(const bf16x8*)(b0 + (wr * 8 + m) * 1024 + lane * 16);
#pragma unroll
    for (int n = 0; n < 2; ++n)
      bfr[n] = *(const bf16x8*)(b0 + 16384 + (wc * 2 + n) * 1024 + lane * 16);
    if (st) stageA(k0n, b2);
    block_sync();
    asm volatile("s_waitcnt lgkmcnt(0)" ::: "memory");
    __builtin_amdgcn_sched_barrier(0);
    __builtin_amdgcn_s_setprio(1);
#pragma unroll
    for (int m = 0; m < 4; ++m)
#pragma unroll
      for (int n = 0; n < 2; ++n)
        acc[m][n] = __builtin_amdgcn_mfma_f32_16x16x32_bf16(af[m], bfr[n], acc[m][n], 0, 0, 0);
    __builtin_amdgcn_s_setprio(0);
    block_sync();
    // P2
#pragma unroll
    for (int m = 0; m < 4; ++m)
      af[m] = *(const bf16x8*)(b0 + (wr * 8 + 4 + m) * 1024 + lane * 16);
    if (st) stageB(k0n, b2);
    block_sync();
    asm volatile("s_waitcnt lgkmcnt(0)" ::: "memory");
    __builtin_amdgcn_sched_barrier(0);
    __builtin_amdgcn_s_setprio(1);
#pragma unroll
    for (int m = 0; m < 4; ++m)
#pragma unroll
      for (int n = 0; n < 2; ++n)
        acc[4 + m][n] = __builtin_amdgcn_mfma_f32_16x16x32_bf16(af[m], bfr[n], acc[4 + m][n], 0, 0, 0);
    __builtin_amdgcn_s_setprio(0);
    if (st) asm volatile("s_waitcnt vmcnt(3)" ::: "memory");
    else if (it + 1 < 32) asm volatile("s_waitcnt vmcnt(0)" ::: "memory");
    block_sync();
    char* tmp = b0; b0 = b1; b1 = b2; b2 = tmp;
  }

#pragma unroll
  for (int n = 0; n < 2; ++n) {
    const int col = n0 + wc * 32 + n * 16 + ln15;
    const float bv = bias[col];
#pragma unroll
    for (int m = 0; m < 8; ++m)
#pragma unroll
      for (int j = 0; j < 4; ++j) {
        const int row = m0 + wr * 128 + m * 16 + lhi * 4 + j;
        out[(size_t)row * 1024 + col] = acc[m][n][j] + bv;
      }
  }
}

extern "C" void kernel_launch(void* const* d_in, const int* in_sizes, int n_in,
                              void* d_out, int out_size, void* d_ws, size_t ws_size,
                              hipStream_t stream) {
  (void)in_sizes; (void)n_in; (void)out_size; (void)ws_size;
  const float* x      = (const float*)d_in[0];
  const int*   dirp   = (const int*)d_in[1];
  const float* qkv_w  = (const float*)d_in[2];
  const float* qkv_b  = (const float*)d_in[3];
  const float* proj_w = (const float*)d_in[4];
  const float* proj_b = (const float*)d_in[5];
  float* out = (float*)d_out;

  char* ws = (char*)d_ws;
  bf16_t* xb   = (bf16_t*)(ws);                       // 16,777,216 B (reused as a2)
  bf16_t* wq_t = (bf16_t*)(ws + 16777216);            //  6,291,456 B
  bf16_t* wp_t = (bf16_t*)(ws + 23068672);            //  2,097,152 B
  bf16_t* qb   = (bf16_t*)(ws + 25165824);            // 16,777,216 B
  bf16_t* kb   = (bf16_t*)(ws + 41943040);            // 16,777,216 B
  bf16_t* vtb  = (bf16_t*)(ws + 58720256);            // 16,777,216 B (end: 75,497,472)
  bf16_t* a2   = xb;

  k_cast<<<8192, 256, 0, stream>>>(x, xb, 2097152);
  k_transpose_cast<<<dim3(96, 32), dim3(32, 8), 0, stream>>>(qkv_w, wq_t, 1024, 3072);
  k_transpose_cast<<<dim3(32, 32), dim3(32, 8), 0, stream>>>(proj_w, wp_t, 1024, 1024);
  k_gemm_qkv<<<dim3(32, 8), 512, 0, stream>>>(xb, wq_t, qkv_b, qb, kb, vtb);
  k_attn4<<<dim3(64, 8), 256, 0, stream>>>(qb, kb, vtb, dirp, a2);
  k_gemm_proj<<<dim3(32, 8), 512, 0, stream>>>(a2, wp_t, proj_b, out);
}

// Round 15
// 192.617 us; speedup vs baseline: 1.6704x; 1.1101x over previous
//
#include <hip/hip_runtime.h>
#include <math.h>

typedef __bf16 bf16_t;
typedef bf16_t bf16x8 __attribute__((ext_vector_type(8)));
typedef bf16_t bf16x4 __attribute__((ext_vector_type(4)));
typedef float  f32x4  __attribute__((ext_vector_type(4)));
typedef float  floatv4 __attribute__((ext_vector_type(4)));

#define AS1 __attribute__((address_space(1)))
#define AS3 __attribute__((address_space(3)))

static __device__ __forceinline__ void gld_lds16(const void* g, void* l) {
  __builtin_amdgcn_global_load_lds((const AS1 unsigned int*)g,
                                   (AS3 unsigned int*)l, 16, 0, 0);
}
static __device__ __forceinline__ void block_sync() {
  asm volatile("" ::: "memory");
  __builtin_amdgcn_s_barrier();
  asm volatile("" ::: "memory");
}

// ---------------- cast f32 -> bf16, 8 elems/thread ----------------
__global__ __launch_bounds__(256) void k_cast(const float* __restrict__ in,
                                              bf16_t* __restrict__ out, int n8) {
  int i = blockIdx.x * 256 + threadIdx.x;
  if (i >= n8) return;
  floatv4 v0 = ((const floatv4*)in)[i * 2];
  floatv4 v1 = ((const floatv4*)in)[i * 2 + 1];
  bf16x8 o;
  o[0] = (bf16_t)v0.x; o[1] = (bf16_t)v0.y; o[2] = (bf16_t)v0.z; o[3] = (bf16_t)v0.w;
  o[4] = (bf16_t)v1.x; o[5] = (bf16_t)v1.y; o[6] = (bf16_t)v1.z; o[7] = (bf16_t)v1.w;
  ((bf16x8*)out)[i] = o;
}

// ---------------- transpose + cast: in f32 [R][Cc] -> out bf16 [Cc][R] ----------------
__global__ __launch_bounds__(256) void k_transpose_cast(const float* __restrict__ in,
                                                        bf16_t* __restrict__ out,
                                                        int R, int Cc) {
  __shared__ float tile[32][33];
  int c0 = blockIdx.x * 32, r0 = blockIdx.y * 32;
  int tx = threadIdx.x, ty = threadIdx.y;  // 32 x 8
#pragma unroll
  for (int i = 0; i < 32; i += 8)
    tile[ty + i][tx] = in[(size_t)(r0 + ty + i) * Cc + c0 + tx];
  __syncthreads();
#pragma unroll
  for (int i = 0; i < 32; i += 8)
    out[(size_t)(c0 + ty + i) * R + r0 + tx] = (bf16_t)tile[tx][ty + i];
}

// ============ GEMM1 v6 (best measured: 89.3us): 256x384, BK=32, 8 waves, grid 32x8 ============
__global__ __launch_bounds__(512, 2) void k_gemm_qkv(
    const bf16_t* __restrict__ A, const bf16_t* __restrict__ Bt,
    const float* __restrict__ bias,
    bf16_t* __restrict__ qo, bf16_t* __restrict__ ko, bf16_t* __restrict__ vto) {
  const int K = 1024;
  __shared__ __align__(16) char smem[122880];  // 3 x 40KB; epilogue reuses 68KB
  const int m0 = blockIdx.x * 256, n0 = blockIdx.y * 384;
  const int t = threadIdx.x, lane = t & 63, wv = t >> 6;
  const int ln15 = lane & 15, lhi = lane >> 4;
  const int wr = wv >> 2, wc = wv & 3;  // 2M x 4N; per-wave 128 x 96

  f32x4 acc[8][6];
#pragma unroll
  for (int m = 0; m < 8; ++m)
#pragma unroll
    for (int n = 0; n < 6; ++n) acc[m][n] = (f32x4){0.f, 0.f, 0.f, 0.f};
  bf16x8 af[4], bfr[6];

  const bf16_t* aS = A + (size_t)(m0 + wv * 16 + ln15) * K + lhi * 8;
  const bf16_t* bS = Bt + (size_t)(n0 + wv * 16 + ln15) * K + lhi * 8;
  const int dA = wv * 1024 + lane * 16;

  auto stageA = [&](int k0, char* buf) {
    gld_lds16(aS + k0, buf + dA);
    gld_lds16(aS + (size_t)128 * K + k0, buf + 8192 + dA);
  };
  auto stageB = [&](int k0, char* buf) {
    gld_lds16(bS + k0, buf + 16384 + dA);
    gld_lds16(bS + (size_t)128 * K + k0, buf + 24576 + dA);
    gld_lds16(bS + (size_t)256 * K + k0, buf + 32768 + dA);
  };

  char* b0 = smem;
  char* b1 = smem + 40960;
  char* b2 = smem + 81920;
  stageA(0, b0); stageB(0, b0);
  stageA(32, b1); stageB(32, b1);
  asm volatile("s_waitcnt vmcnt(5)" ::: "memory");
  block_sync();

#pragma unroll 1
  for (int it = 0; it < 32; ++it) {
    const bool st = (it + 2 < 32);
    const int k0n = (it + 2) * 32;
    // P1: m-rows 0..3 x all 6 n
#pragma unroll
    for (int m = 0; m < 4; ++m)
      af[m] = *(const bf16x8*)(b0 + (wr * 8 + m) * 1024 + lane * 16);
#pragma unroll
    for (int n = 0; n < 6; ++n)
      bfr[n] = *(const bf16x8*)(b0 + 16384 + (wc * 6 + n) * 1024 + lane * 16);
    if (st) stageA(k0n, b2);
    block_sync();
    asm volatile("s_waitcnt lgkmcnt(0)" ::: "memory");
    __builtin_amdgcn_sched_barrier(0);
    __builtin_amdgcn_s_setprio(1);
#pragma unroll
    for (int m = 0; m < 4; ++m)
#pragma unroll
      for (int n = 0; n < 6; ++n)
        acc[m][n] = __builtin_amdgcn_mfma_f32_16x16x32_bf16(af[m], bfr[n], acc[m][n], 0, 0, 0);
    __builtin_amdgcn_s_setprio(0);
    block_sync();
    // P2: m-rows 4..7
#pragma unroll
    for (int m = 0; m < 4; ++m)
      af[m] = *(const bf16x8*)(b0 + (wr * 8 + 4 + m) * 1024 + lane * 16);
    if (st) stageB(k0n, b2);
    block_sync();
    asm volatile("s_waitcnt lgkmcnt(0)" ::: "memory");
    __builtin_amdgcn_sched_barrier(0);
    __builtin_amdgcn_s_setprio(1);
#pragma unroll
    for (int m = 0; m < 4; ++m)
#pragma unroll
      for (int n = 0; n < 6; ++n)
        acc[4 + m][n] = __builtin_amdgcn_mfma_f32_16x16x32_bf16(af[m], bfr[n], acc[4 + m][n], 0, 0, 0);
    __builtin_amdgcn_s_setprio(0);
    if (st) asm volatile("s_waitcnt vmcnt(5)" ::: "memory");
    else if (it + 1 < 32) asm volatile("s_waitcnt vmcnt(0)" ::: "memory");
    block_sync();
    char* tmp = b0; b0 = b1; b1 = b2; b2 = tmp;
  }

  // epilogue: 3 passes of 128 cols through LDS; pass boundaries align with q/k/v (1024%128==0)
  bf16_t* L = (bf16_t*)smem;
  const int bq = m0 >> 11, ttb = m0 & 2047;
#pragma unroll 1
  for (int p = 0; p < 3; ++p) {
    const int wcol0 = n0 + p * 128;
    const int which = wcol0 >> 10;  // uniform per pass
    const float bscale = (which == 0) ? 0.18033688011112042f : 1.0f;  // 0.125*log2(e)
#pragma unroll
    for (int n = 0; n < 6; ++n) {
      const int c16 = wc * 6 + n;
      if ((c16 >> 3) == p) {
        const int colL = c16 * 16 - p * 128 + ln15;
        const float bv = bias[n0 + c16 * 16 + ln15];
#pragma unroll
        for (int m = 0; m < 8; ++m)
#pragma unroll
          for (int j = 0; j < 4; ++j) {
            const int row = wr * 128 + m * 16 + lhi * 4 + j;
            const bf16_t ob = (bf16_t)((acc[m][n][j] + bv) * bscale);
            if (which == 2) L[colL * 264 + row] = ob;   // v: col-major [128][264]
            else            L[row * 132 + colL] = ob;   // q/k: row-major [256][132]
          }
      }
    }
    block_sync();
    if (which == 2) {
#pragma unroll
      for (int c = 0; c < 8; ++c) {
        const int idx = c * 512 + t;
        const int vcol = idx >> 5, r8 = (idx & 31) * 8;
        bf16x8 v8 = *(const bf16x8*)&L[vcol * 264 + r8];
        const int cc = (wcol0 & 1023) + vcol;
        const int hh = cc >> 6, d = cc & 63;
        *(bf16x8*)&vto[((size_t)(bq * 16 + hh) * 64 + d) * 2048 + ttb + r8] = v8;
      }
    } else {
      bf16_t* dst = (which == 0) ? qo : ko;
#pragma unroll
      for (int c = 0; c < 8; ++c) {
        const int idx = c * 512 + t;
        const int row = idx >> 4, c8 = (idx & 15) * 8;
        bf16x8 v8 = *(const bf16x8*)&L[row * 132 + c8];
        const int cc = (wcol0 & 1023) + c8;
        const int hh = cc >> 6, d = cc & 63;
        *(bf16x8*)&dst[((size_t)(bq * 16 + hh) * 2048 + ttb + row) * 64 + d] = v8;
      }
    }
    block_sync();
  }
}

// ---------------- flash attention v4: 32 q-rows/wave (2 groups share K/V frags) ----------------
__global__ __launch_bounds__(256) void k_attn4(
    const bf16_t* __restrict__ q, const bf16_t* __restrict__ k,
    const bf16_t* __restrict__ vt, const int* __restrict__ dirp,
    bf16_t* __restrict__ a2) {
  const int T = 2048;
  __shared__ __align__(16) bf16_t smem[16384];  // 32 KB: 2 bufs x 16KB
  const int bh = blockIdx.x, b = bh >> 4, h = bh & 15;
  const int jb = blockIdx.y;  // 0..7
  const int t = threadIdx.x, lane = t & 63, wv = t >> 6;
  const int ln15 = lane & 15, lhi = lane >> 4;
  const bool anti = (*dirp == 1);

  const bf16_t* kbase = k + (size_t)bh * T * 64;
  const bf16_t* vbase = vt + (size_t)bh * 64 * T;

  auto stage = [&](int kc0, int buf) {
    char* Kd = (char*)smem + buf * 16384;
    char* Vd = Kd + 8192;
#pragma unroll
    for (int s = 0; s < 2; ++s) {
      const int qk = s * 4 + wv;
      const int krow = kc0 + (qk >> 2) * 32 + ((qk >> 1) & 1) * 4 +
                       ((lane & 15) >> 2) * 8 + (lane & 3);
      const int kcolb = (lane >> 4) * 16 + (qk & 1) * 64;
      gld_lds16((const char*)kbase + (size_t)krow * 128 + kcolb,
                Kd + s * 4096 + t * 16);
      const int vd = (qk & 3) * 16 + (lane & 15);
      gld_lds16((const char*)vbase + (size_t)vd * 4096 + (size_t)kc0 * 2 +
                    (qk >> 2) * 64 + (lane >> 4) * 16,
                Vd + s * 4096 + t * 16);
    }
  };

#pragma unroll 1
  for (int sel = 0; sel < 2; ++sel) {
    const int qt = sel ? (15 - jb) : jb;     // q-tile of 128 rows
    const int q0w = qt * 128 + wv * 32;      // this wave's 32 rows

    bf16x8 qf[2][2];
#pragma unroll
    for (int g = 0; g < 2; ++g) {
      const bf16_t* qp = q + ((size_t)bh * T + q0w + g * 16 + ln15) * 64 + lhi * 8;
      qf[g][0] = *(const bf16x8*)qp;
      qf[g][1] = *(const bf16x8*)(qp + 32);
    }

    f32x4 acc[2][4];
#pragma unroll
    for (int g = 0; g < 2; ++g)
#pragma unroll
      for (int dg = 0; dg < 4; ++dg) acc[g][dg] = (f32x4){0.f, 0.f, 0.f, 0.f};
    float mrun[2] = {-3.0e38f, -3.0e38f}, lrun[2] = {0.f, 0.f};

    const int kt0 = anti ? 2 * qt : 0;
    const int nb  = anti ? (32 - 2 * qt) : (2 * qt + 2);

    stage(kt0 * 64, 0);
#pragma unroll 1
    for (int i = 0; i < nb; ++i) {
      const int kt = kt0 + i;
      const int buf = i & 1;
      if (i + 1 < nb) {
        stage((kt + 1) * 64, buf ^ 1);
        asm volatile("s_waitcnt vmcnt(4)" ::: "memory");
      } else {
        asm volatile("s_waitcnt vmcnt(0)" ::: "memory");
      }
      block_sync();
      const bf16_t* Kb = smem + buf * 8192;  // bf16 units
      const bf16_t* Vb = Kb + 4096;

      const bool active = anti ? (kt * 64 + 63 >= q0w) : (kt * 64 <= q0w + 31);
      if (active) {
        float sc[2][16];
#pragma unroll
        for (int kh = 0; kh < 2; ++kh) {
          bf16x8 kf0 = *(const bf16x8*)(Kb + (kh * 4 + 0) * 512 + lane * 8);
          bf16x8 kf1 = *(const bf16x8*)(Kb + (kh * 4 + 1) * 512 + lane * 8);
          bf16x8 kf2 = *(const bf16x8*)(Kb + (kh * 4 + 2) * 512 + lane * 8);
          bf16x8 kf3 = *(const bf16x8*)(Kb + (kh * 4 + 3) * 512 + lane * 8);
#pragma unroll
          for (int g = 0; g < 2; ++g) {
            const f32x4 zz = (f32x4){0.f, 0.f, 0.f, 0.f};
            f32x4 slo = __builtin_amdgcn_mfma_f32_16x16x32_bf16(kf0, qf[g][0], zz, 0, 0, 0);
            slo = __builtin_amdgcn_mfma_f32_16x16x32_bf16(kf1, qf[g][1], slo, 0, 0, 0);
            f32x4 shi = __builtin_amdgcn_mfma_f32_16x16x32_bf16(kf2, qf[g][0], zz, 0, 0, 0);
            shi = __builtin_amdgcn_mfma_f32_16x16x32_bf16(kf3, qf[g][1], shi, 0, 0, 0);
#pragma unroll
            for (int j = 0; j < 4; ++j) {
              sc[g][kh * 8 + j] = slo[j];
              sc[g][kh * 8 + 4 + j] = shi[j];
            }
          }
        }
        bf16x8 vfr[8];
#pragma unroll
        for (int dg = 0; dg < 8; ++dg)
          vfr[dg] = *(const bf16x8*)(Vb + dg * 512 + lane * 8);
#pragma unroll
        for (int g = 0; g < 2; ++g) {
          const int grow = q0w + g * 16 + ln15;
          const bool needm = anti ? (kt * 64 < q0w + g * 16 + 15)
                                  : (kt * 64 + 63 > q0w + g * 16);
          if (needm) {
#pragma unroll
            for (int e = 0; e < 16; ++e) {
              const int col = kt * 64 + (e >> 3) * 32 + lhi * 8 + (e & 7);
              const bool ok = anti ? (col >= grow) : (col <= grow);
              sc[g][e] = ok ? sc[g][e] : -3.0e38f;
            }
          }
          float lmax = sc[g][0];
#pragma unroll
          for (int e = 1; e < 16; ++e) lmax = fmaxf(lmax, sc[g][e]);
          if (!__all(lmax <= mrun[g] + 8.f)) {
            float vm = lmax;
            vm = fmaxf(vm, __shfl_xor(vm, 16));
            vm = fmaxf(vm, __shfl_xor(vm, 32));
            const float mn = fmaxf(mrun[g], vm);
            const float al = __builtin_amdgcn_exp2f(mrun[g] - mn);
            lrun[g] *= al;
#pragma unroll
            for (int dg = 0; dg < 4; ++dg) acc[g][dg] *= al;
            mrun[g] = mn;
          }
          bf16x8 pb0, pb1;
          float rs = 0.f;
#pragma unroll
          for (int e = 0; e < 8; ++e) {
            float p = __builtin_amdgcn_exp2f(sc[g][e] - mrun[g]);
            rs += p; pb0[e] = (bf16_t)p;
          }
#pragma unroll
          for (int e = 0; e < 8; ++e) {
            float p = __builtin_amdgcn_exp2f(sc[g][8 + e] - mrun[g]);
            rs += p; pb1[e] = (bf16_t)p;
          }
          lrun[g] += rs;
#pragma unroll
          for (int dg = 0; dg < 4; ++dg)
            acc[g][dg] = __builtin_amdgcn_mfma_f32_16x16x32_bf16(vfr[dg], pb0, acc[g][dg], 0, 0, 0);
#pragma unroll
          for (int dg = 0; dg < 4; ++dg)
            acc[g][dg] = __builtin_amdgcn_mfma_f32_16x16x32_bf16(vfr[4 + dg], pb1, acc[g][dg], 0, 0, 0);
        }
      }
      block_sync();
    }

#pragma unroll
    for (int g = 0; g < 2; ++g) {
      float l = lrun[g];
      l += __shfl_xor(l, 16);
      l += __shfl_xor(l, 32);
      const float inv = __builtin_amdgcn_rcpf(l);
      bf16_t* op = a2 + ((size_t)b * T + q0w + g * 16 + ln15) * 1024 + h * 64 + lhi * 4;
#pragma unroll
      for (int dg = 0; dg < 4; ++dg) {
        bf16x4 o4;
#pragma unroll
        for (int jx = 0; jx < 4; ++jx) o4[jx] = (bf16_t)(acc[g][dg][jx] * inv);
        *(bf16x4*)(op + dg * 16) = o4;
      }
    }
  }
}

// ============ GEMM2 v6 (best measured): 256x128, BK=32, 8 waves, grid 32x8 ============
__global__ __launch_bounds__(512, 2) void k_gemm_proj(
    const bf16_t* __restrict__ A, const bf16_t* __restrict__ Bt,
    const float* __restrict__ bias, float* __restrict__ out) {
  const int K = 1024;
  __shared__ __align__(16) char smem[73728];  // 3 x 24KB
  const int m0 = blockIdx.x * 256, n0 = blockIdx.y * 128;
  const int t = threadIdx.x, lane = t & 63, wv = t >> 6;
  const int ln15 = lane & 15, lhi = lane >> 4;
  const int wr = wv >> 2, wc = wv & 3;  // 2M x 4N; per-wave 128 x 32

  f32x4 acc[8][2];
#pragma unroll
  for (int m = 0; m < 8; ++m)
#pragma unroll
    for (int n = 0; n < 2; ++n) acc[m][n] = (f32x4){0.f, 0.f, 0.f, 0.f};
  bf16x8 af[4], bfr[2];

  const bf16_t* aS = A + (size_t)(m0 + wv * 16 + ln15) * K + lhi * 8;
  const bf16_t* bS = Bt + (size_t)(n0 + wv * 16 + ln15) * K + lhi * 8;
  const int dA = wv * 1024 + lane * 16;

  auto stageA = [&](int k0, char* buf) {
    gld_lds16(aS + k0, buf + dA);
    gld_lds16(aS + (size_t)128 * K + k0, buf + 8192 + dA);
  };
  auto stageB = [&](int k0, char* buf) {
    gld_lds16(bS + k0, buf + 16384 + dA);
  };

  char* b0 = smem;
  char* b1 = smem + 24576;
  char* b2 = smem + 49152;
  stageA(0, b0); stageB(0, b0);
  stageA(32, b1); stageB(32, b1);
  asm volatile("s_waitcnt vmcnt(3)" ::: "memory");
  block_sync();

#pragma unroll 1
  for (int it = 0; it < 32; ++it) {
    const bool st = (it + 2 < 32);
    const int k0n = (it + 2) * 32;
    // P1
#pragma unroll
    for (int m = 0; m < 4; ++m)
      af[m] = *(const bf16x8*)(b0 + (wr * 8 + m) * 1024 + lane * 16);
#pragma unroll
    for (int n = 0; n < 2; ++n)
      bfr[n] = *(const bf16x8*)(b0 + 16384 + (wc * 2 + n) * 1024 + lane * 16);
    if (st) stageA(k0n, b2);
    block_sync();
    asm volatile("s_waitcnt lgkmcnt(0)" ::: "memory");
    __builtin_amdgcn_sched_barrier(0);
    __builtin_amdgcn_s_setprio(1);
#pragma unroll
    for (int m = 0; m < 4; ++m)
#pragma unroll
      for (int n = 0; n < 2; ++n)
        acc[m][n] = __builtin_amdgcn_mfma_f32_16x16x32_bf16(af[m], bfr[n], acc[m][n], 0, 0, 0);
    __builtin_amdgcn_s_setprio(0);
    block_sync();
    // P2
#pragma unroll
    for (int m = 0; m < 4; ++m)
      af[m] = *(const bf16x8*)(b0 + (wr * 8 + 4 + m) * 1024 + lane * 16);
    if (st) stageB(k0n, b2);
    block_sync();
    asm volatile("s_waitcnt lgkmcnt(0)" ::: "memory");
    __builtin_amdgcn_sched_barrier(0);
    __builtin_amdgcn_s_setprio(1);
#pragma unroll
    for (int m = 0; m < 4; ++m)
#pragma unroll
      for (int n = 0; n < 2; ++n)
        acc[4 + m][n] = __builtin_amdgcn_mfma_f32_16x16x32_bf16(af[m], bfr[n], acc[4 + m][n], 0, 0, 0);
    __builtin_amdgcn_s_setprio(0);
    if (st) asm volatile("s_waitcnt vmcnt(3)" ::: "memory");
    else if (it + 1 < 32) asm volatile("s_waitcnt vmcnt(0)" ::: "memory");
    block_sync();
    char* tmp = b0; b0 = b1; b1 = b2; b2 = tmp;
  }

#pragma unroll
  for (int n = 0; n < 2; ++n) {
    const int col = n0 + wc * 32 + n * 16 + ln15;
    const float bv = bias[col];
#pragma unroll
    for (int m = 0; m < 8; ++m)
#pragma unroll
      for (int j = 0; j < 4; ++j) {
        const int row = m0 + wr * 128 + m * 16 + lhi * 4 + j;
        out[(size_t)row * 1024 + col] = acc[m][n][j] + bv;
      }
  }
}

extern "C" void kernel_launch(void* const* d_in, const int* in_sizes, int n_in,
                              void* d_out, int out_size, void* d_ws, size_t ws_size,
                              hipStream_t stream) {
  (void)in_sizes; (void)n_in; (void)out_size; (void)ws_size;
  const float* x      = (const float*)d_in[0];
  const int*   dirp   = (const int*)d_in[1];
  const float* qkv_w  = (const float*)d_in[2];
  const float* qkv_b  = (const float*)d_in[3];
  const float* proj_w = (const float*)d_in[4];
  const float* proj_b = (const float*)d_in[5];
  float* out = (float*)d_out;

  char* ws = (char*)d_ws;
  bf16_t* xb   = (bf16_t*)(ws);                       // 16,777,216 B (reused as a2)
  bf16_t* wq_t = (bf16_t*)(ws + 16777216);            //  6,291,456 B
  bf16_t* wp_t = (bf16_t*)(ws + 23068672);            //  2,097,152 B
  bf16_t* qb   = (bf16_t*)(ws + 25165824);            // 16,777,216 B
  bf16_t* kb   = (bf16_t*)(ws + 41943040);            // 16,777,216 B
  bf16_t* vtb  = (bf16_t*)(ws + 58720256);            // 16,777,216 B (end: 75,497,472)
  bf16_t* a2   = xb;

  k_cast<<<4096, 256, 0, stream>>>(x, xb, 1048576);
  k_transpose_cast<<<dim3(96, 32), dim3(32, 8), 0, stream>>>(qkv_w, wq_t, 1024, 3072);
  k_transpose_cast<<<dim3(32, 32), dim3(32, 8), 0, stream>>>(proj_w, wp_t, 1024, 1024);
  k_gemm_qkv<<<dim3(32, 8), 512, 0, stream>>>(xb, wq_t, qkv_b, qb, kb, vtb);
  k_attn4<<<dim3(64, 8), 256, 0, stream>>>(qb, kb, vtb, dirp, a2);
  k_gemm_proj<<<dim3(32, 8), 512, 0, stream>>>(a2, wp_t, proj_b, out);
}